// Round 8
// baseline (110.631 us; speedup 1.0000x reference)
//
#include <hip/hip_runtime.h>
#include <hip/hip_bf16.h>

typedef __bf16 bf16;
typedef __bf16 bf16x2 __attribute__((ext_vector_type(2)));
typedef __bf16 bf16x4 __attribute__((ext_vector_type(4)));
typedef __bf16 bf16x8 __attribute__((ext_vector_type(8)));
typedef float  f32x4  __attribute__((ext_vector_type(4)));

static __device__ __forceinline__ f32x4 mfma16(bf16x8 a, bf16x8 b, f32x4 c) {
  return __builtin_amdgcn_mfma_f32_16x16x32_bf16(a, b, c, 0, 0, 0);
}

static __device__ __forceinline__ void gload_lds16(const bf16* g, bf16* l) {
  __builtin_amdgcn_global_load_lds(
      (const __attribute__((address_space(1))) void*)g,
      (__attribute__((address_space(3))) void*)l, 16, 0, 0);
}

#define VMCNT0() asm volatile("s_waitcnt vmcnt(0)" ::: "memory")
#define BARRIER()                                        \
  do {                                                   \
    __builtin_amdgcn_sched_barrier(0);                   \
    asm volatile("" ::: "memory");                       \
    __builtin_amdgcn_s_barrier();                        \
    asm volatile("" ::: "memory");                       \
    __builtin_amdgcn_sched_barrier(0);                   \
  } while (0)

// ---------------- fp32 -> bf16 weight cast (both weights, one launch) ----------------
__global__ __launch_bounds__(256) void cvt2_kernel(const float* __restrict__ wa,
                                                   bf16* __restrict__ oa,
                                                   const float* __restrict__ wb,
                                                   bf16* __restrict__ ob) {
  int i = blockIdx.x * 256 + threadIdx.x;
  const int na4 = 3072 * 1024 / 4;
  const float* src; bf16* dst;
  if (i < na4) { src = wa; dst = oa; }
  else         { src = wb; dst = ob; i -= na4; }
  float4 v = ((const float4*)src)[i];
  bf16x4 o = { (bf16)v.x, (bf16)v.y, (bf16)v.z, (bf16)v.w };
  *(bf16x4*)(dst + 4ll * i) = o;
}

// ---------------- GroupNorm -> xnT (b, t, c) bf16 ----------------
__global__ __launch_bounds__(512) void gn_kernel(const float* __restrict__ x,
                                                 const float* __restrict__ w,
                                                 const float* __restrict__ bias,
                                                 bf16* __restrict__ xnT) {
  int id = blockIdx.x;
  int b = id >> 7, g = (id >> 2) & 31, qtr = id & 3;
  const float* xb = x + ((size_t)b * 1024 + g * 32) * 1024;   // 32 ch x 1024 t
  int tid = threadIdx.x;
  float s = 0.f, sq = 0.f;
  const float4* x4 = (const float4*)xb;
  for (int i = tid; i < 8192; i += 512) {
    float4 v = x4[i];
    s  += v.x + v.y + v.z + v.w;
    sq += v.x * v.x + v.y * v.y + v.z * v.z + v.w * v.w;
  }
#pragma unroll
  for (int off = 32; off; off >>= 1) { s += __shfl_down(s, off); sq += __shfl_down(sq, off); }
  __shared__ float red[16];
  int wv = tid >> 6;
  if ((tid & 63) == 0) { red[wv] = s; red[8 + wv] = sq; }
  __syncthreads();
  s = 0.f; sq = 0.f;
#pragma unroll
  for (int i = 0; i < 8; ++i) { s += red[i]; sq += red[8 + i]; }
  float mean = s * (1.f / 32768.f);
  float var  = sq * (1.f / 32768.f) - mean * mean;
  float rstd = rsqrtf(var + 1e-5f);

  __shared__ bf16 tile[64][36];
  int c = tid >> 4, q = tid & 15;              // load role: ch c, t-quad q
  int r = tid >> 3, q2 = tid & 7;              // store role: row r, ch-quad q2
  float wc = w[g * 32 + c] * rstd;
  float fb = bias[g * 32 + c] - mean * wc;
  for (int t0 = qtr * 256; t0 < qtr * 256 + 256; t0 += 64) {
    float4 v = *(const float4*)(xb + (size_t)c * 1024 + t0 + q * 4);
    tile[q * 4 + 0][c] = (bf16)(v.x * wc + fb);
    tile[q * 4 + 1][c] = (bf16)(v.y * wc + fb);
    tile[q * 4 + 2][c] = (bf16)(v.z * wc + fb);
    tile[q * 4 + 3][c] = (bf16)(v.w * wc + fb);
    __syncthreads();
    *(bf16x4*)&xnT[((size_t)b * 1024 + t0 + r) * 1024 + g * 32 + q2 * 4] =
        *(bf16x4*)&tile[r][q2 * 4];
    __syncthreads();
  }
}

// ---------------- QKV GEMM: 256x192x64, 2-phase pipelined, 8 waves ----------------
__global__ __launch_bounds__(512, 1) void qkv_kernel(
    const bf16* __restrict__ A, const bf16* __restrict__ Bw,
    const float* __restrict__ bias,
    bf16* __restrict__ qkT, bf16* __restrict__ vC) {
  extern __shared__ __align__(16) bf16 smem[];
  // bytes: A(d,h) @ d*32768 + h*16384 (128x64 each); B(d) @ 65536 + d*24576 (192x64)

  int tid = threadIdx.x, wid = tid >> 6, lane = tid & 63;
  int l15 = lane & 15, l4 = lane >> 4;
  int wr = wid >> 2, wc = wid & 3;
  int rsw = (l15 & 7) << 4;

  int sid = (blockIdx.x & 7) * 32 + (blockIdx.x >> 3);   // XCD chunk swizzle (256%8==0)
  int bx = sid & 15, by = (sid >> 4) & 3, z = sid >> 6;
  int m0 = by * 256, n0 = bx * 192;
  const bf16* Ab = A + (size_t)z * 1024 * 1024 + (size_t)m0 * 1024;
  const bf16* Bb = Bw + (size_t)n0 * 1024;

  int srow = tid >> 3;                    // 0..63
  int csw  = (tid & 7) ^ (srow & 7);      // pre-swizzled source chunk
  auto stageA = [&](int d, int h, int kt) {
    bf16* dst = smem + d * 16384 + h * 8192;
    const bf16* src = Ab + (size_t)(h * 128) * 1024 + kt * 64 + csw * 8;
#pragma unroll
    for (int L = 0; L < 2; ++L)
      gload_lds16(src + (size_t)(L * 64 + srow) * 1024, dst + (L * 512 + wid * 64) * 8);
  };
  auto stageB = [&](int d, int kt) {
    bf16* dst = smem + 32768 + d * 12288;
    const bf16* src = Bb + kt * 64 + csw * 8;
#pragma unroll
    for (int L = 0; L < 3; ++L)
      gload_lds16(src + (size_t)(L * 64 + srow) * 1024, dst + (L * 512 + wid * 64) * 8);
  };

  f32x4 acc[8][3] = {};

  stageA(0, 0, 0); stageA(0, 1, 0); stageB(0, 0);
  VMCNT0();
  BARRIER();

  for (int t = 0; t < 16; ++t) {
    int d = t & 1;
    const char* Ab8 = (const char*)smem + d * 32768 + wr * 16384;
    const char* Bb8 = (const char*)smem + 65536 + d * 24576;

    // ---- phase 0: B frags (held all tile) + A rows 0..63; stage A(t+1) ----
    bf16x8 bfr[3][2], af[4][2];
#pragma unroll
    for (int ni = 0; ni < 3; ++ni) {
      int rb = (wc * 48 + ni * 16 + l15) * 128;
#pragma unroll
      for (int kk = 0; kk < 2; ++kk)
        bfr[ni][kk] = *(const bf16x8*)(Bb8 + rb + ((kk * 64 + l4 * 16) ^ rsw));
    }
#pragma unroll
    for (int mi = 0; mi < 4; ++mi) {
      int rb = (mi * 16 + l15) * 128;
#pragma unroll
      for (int kk = 0; kk < 2; ++kk)
        af[mi][kk] = *(const bf16x8*)(Ab8 + rb + ((kk * 64 + l4 * 16) ^ rsw));
    }
    if (t < 15) { stageA(d ^ 1, 0, t + 1); stageA(d ^ 1, 1, t + 1); }
    BARRIER();
    __builtin_amdgcn_s_setprio(1);
#pragma unroll
    for (int mi = 0; mi < 4; ++mi)
#pragma unroll
      for (int ni = 0; ni < 3; ++ni)
#pragma unroll
        for (int kk = 0; kk < 2; ++kk)
          acc[mi][ni] = mfma16(af[mi][kk], bfr[ni][kk], acc[mi][ni]);
    __builtin_amdgcn_s_setprio(0);
    BARRIER();

    // ---- phase 1: A rows 64..127; stage B(t+1); drain ----
#pragma unroll
    for (int mi = 0; mi < 4; ++mi) {
      int rb = ((4 + mi) * 16 + l15) * 128;
#pragma unroll
      for (int kk = 0; kk < 2; ++kk)
        af[mi][kk] = *(const bf16x8*)(Ab8 + rb + ((kk * 64 + l4 * 16) ^ rsw));
    }
    if (t < 15) stageB(d ^ 1, t + 1);
    BARRIER();
    __builtin_amdgcn_s_setprio(1);
#pragma unroll
    for (int mi = 0; mi < 4; ++mi)
#pragma unroll
      for (int ni = 0; ni < 3; ++ni)
#pragma unroll
        for (int kk = 0; kk < 2; ++kk)
          acc[4 + mi][ni] = mfma16(af[mi][kk], bfr[ni][kk], acc[4 + mi][ni]);
    __builtin_amdgcn_s_setprio(0);
    VMCNT0();
    BARRIER();
  }

  // ---- epilogue: bias, q/k scale, split write (single head h = bx) ----
  const float scale = 0.35355339059327373f;   // 64^-0.25
  int h = bx;
#pragma unroll
  for (int ni = 0; ni < 3; ++ni) {
    int oin = wc * 48 + ni * 16;              // 0..176, wave-uniform
    float bv = bias[n0 + oin + l15];
#pragma unroll
    for (int mi = 0; mi < 8; ++mi) {
      int tb = m0 + wr * 128 + mi * 16 + l4 * 4;
      f32x4 v = acc[mi][ni];
      if (oin < 128) {                        // q|k -> qkT[b][t][h*128 + oin]
#pragma unroll
        for (int i = 0; i < 4; ++i)
          qkT[((size_t)z * 1024 + tb + i) * 2048 + h * 128 + oin + l15] =
              (bf16)((v[i] + bv) * scale);
      } else {                                // v -> vC[(b*16+h)][c][t]
        bf16x4 st = { (bf16)(v[0] + bv), (bf16)(v[1] + bv),
                      (bf16)(v[2] + bv), (bf16)(v[3] + bv) };
        *(bf16x4*)&vC[(((size_t)z * 16 + h) * 64 + (oin - 128 + l15)) * 1024 + tb] = st;
      }
    }
  }
}

// ---------------- 128x128x32 bf16 MFMA GEMM (proj: bias + residual) ----------------
template <int MODE>
__global__ __launch_bounds__(256) void gemm_kernel(
    const bf16* __restrict__ A, const bf16* __restrict__ Bw,
    const float* __restrict__ bias,
    bf16* __restrict__ qkT, bf16* __restrict__ vC,
    const float* __restrict__ xres, float* __restrict__ out) {
  __shared__ bf16 At[128 * 32];
  __shared__ bf16 Bt[128 * 32];
  int tid = threadIdx.x;
  int wid = tid >> 6, lane = tid & 63;
  int l15 = lane & 15, l4 = lane >> 4;
  int wm = wid >> 1, wn = wid & 1;
  int z = blockIdx.z;
  int m0 = blockIdx.y * 128, n0 = blockIdx.x * 128;
  const bf16* Ab = A + (size_t)z * 1024 * 1024 + (size_t)m0 * 1024;
  const bf16* Bb = Bw + (size_t)n0 * 1024;

  f32x4 acc[4][4] = {};

  for (int k0 = 0; k0 < 1024; k0 += 32) {
#pragma unroll
    for (int j = 0; j < 2; ++j) {
      int slot = j * 256 + tid;
      int row  = slot >> 2;
      int ck   = (slot & 3) ^ ((row >> 1) & 3);   // pre-swizzled source chunk
      gload_lds16(Ab + (size_t)row * 1024 + k0 + ck * 8, At + (size_t)(j * 256 + wid * 64) * 8);
      gload_lds16(Bb + (size_t)row * 1024 + k0 + ck * 8, Bt + (size_t)(j * 256 + wid * 64) * 8);
    }
    __syncthreads();
    bf16x8 af[4], bfr[4];
#pragma unroll
    for (int mi = 0; mi < 4; ++mi) {
      int row = wm * 64 + mi * 16 + l15;
      int ck  = l4 ^ ((row >> 1) & 3);
      af[mi] = *(const bf16x8*)(At + row * 32 + ck * 8);
    }
#pragma unroll
    for (int nf = 0; nf < 4; ++nf) {
      int row = wn * 64 + nf * 16 + l15;
      int ck  = l4 ^ ((row >> 1) & 3);
      bfr[nf] = *(const bf16x8*)(Bt + row * 32 + ck * 8);
    }
#pragma unroll
    for (int mi = 0; mi < 4; ++mi)
#pragma unroll
      for (int nf = 0; nf < 4; ++nf)
        acc[mi][nf] = mfma16(af[mi], bfr[nf], acc[mi][nf]);
    __syncthreads();
  }

  if (MODE == 1) {
#pragma unroll
    for (int nf = 0; nf < 4; ++nf) {
      int o = n0 + wn * 64 + nf * 16 + l15;
      float bv = bias[o];
#pragma unroll
      for (int mi = 0; mi < 4; ++mi) {
        int tb = m0 + wm * 64 + mi * 16 + l4 * 4;
        size_t base = ((size_t)z * 1024 + o) * 1024 + tb;
        float4 xr = *(const float4*)(xres + base);
        f32x4 v = acc[mi][nf];
        float4 ov = { xr.x + v[0] + bv, xr.y + v[1] + bv,
                      xr.z + v[2] + bv, xr.w + v[3] + bv };
        *(float4*)(out + base) = ov;
      }
    }
  }
}

// ---------------- flash attention v5: 4 waves x 32 t-rows, 2 t-frags/wave ----------------
// Each K-frag / V-frag ds_read feeds TWO MFMA (two Q/P fragments) -> LDS
// bytes/FLOP drops ~45% vs v4. Staging, swizzle, barrier schedule identical.
__global__ __launch_bounds__(256, 2) void attn_kernel(const bf16* __restrict__ qkT,
                                                      const bf16* __restrict__ vC,
                                                      bf16* __restrict__ aT) {
  __shared__ __align__(16) bf16 Kt[2][64 * 64];   // [buf][s][d] swizzled, 16 KB
  __shared__ __align__(16) bf16 Vt[2][64 * 64];   // [buf][c][s] swizzled, 16 KB
  __shared__ __align__(16) bf16 Pt[4][32 * 64];   // per-wave P[t][s], swizzled, 16 KB

  int id = blockIdx.x;
  int sid = (id & 7) * 64 + (id >> 3);            // bijective XCD swizzle (512 % 8 == 0)
  int head = sid >> 3, tblk = sid & 7;
  int b = head >> 4, h = head & 15;
  int t0 = tblk * 128;
  int tid = threadIdx.x, wid = tid >> 6, lane = tid & 63;
  int l15 = lane & 15, l4 = lane >> 4;
  int trow = t0 + wid * 32;                       // 32 t-rows per wave

  const bf16* kbase = qkT + (size_t)b * 1024 * 2048 + h * 128 + 64;
  const bf16* vbase = vC + (size_t)(b * 16 + h) * 64 * 1024;
  char* Pw = (char*)Pt[wid];
  int rsw = (l15 & 7) << 4;                       // row-XOR ((g*16+l15)&7 == l15&7)

  // Q fragments, two t-groups (read once)
  bf16x8 qf[2][2];
#pragma unroll
  for (int g = 0; g < 2; ++g) {
    const bf16* qrow = qkT + ((size_t)b * 1024 + trow + g * 16 + l15) * 2048 + h * 128;
#pragma unroll
    for (int kb = 0; kb < 2; ++kb) qf[g][kb] = *(const bf16x8*)(qrow + kb * 32 + l4 * 8);
  }

  // stage: wave wid owns 8-row groups {2*wid, 2*wid+1} of K and V
  int rl = lane >> 3;
  int scol = (((lane & 7) * 16) ^ (rl << 4)) >> 1;
  auto stage = [&](int buf, int st) {
    int s0 = st * 64;
#pragma unroll
    for (int j = 0; j < 2; ++j) {
      int g8 = wid * 2 + j;
      int r = g8 * 8 + rl;
      gload_lds16(kbase + (size_t)(s0 + r) * 2048 + scol, &Kt[buf][g8 * 512]);
      gload_lds16(vbase + (size_t)r * 1024 + s0 + scol, &Vt[buf][g8 * 512]);
    }
  };

  float m_run[2] = { -1e30f, -1e30f }, l_run[2] = { 0.f, 0.f };
  f32x4 oacc[4][2] = {};                          // O^T[c][t], two t-groups

  stage(0, 0);
  __syncthreads();

  for (int st = 0; st < 16; ++st) {
    int cur = st & 1;
    if (st < 15) stage(cur ^ 1, st + 1);

    // ---- QK^T swapped: S^T[s][t], 16 MFMA (each kf feeds both groups) ----
    const char* Kb = (const char*)Kt[cur];
    f32x4 sf[4][2];
#pragma unroll
    for (int nf = 0; nf < 4; ++nf)
#pragma unroll
      for (int g = 0; g < 2; ++g) sf[nf][g] = (f32x4){0.f, 0.f, 0.f, 0.f};
    __builtin_amdgcn_s_setprio(1);
#pragma unroll
    for (int nf = 0; nf < 4; ++nf) {
      int rr = nf * 16 + l15;
#pragma unroll
      for (int kb = 0; kb < 2; ++kb) {
        bf16x8 kf = *(const bf16x8*)(Kb + rr * 128 + ((kb * 64 + l4 * 16) ^ rsw));
        sf[nf][0] = mfma16(kf, qf[0][kb], sf[nf][0]);
        sf[nf][1] = mfma16(kf, qf[1][kb], sf[nf][1]);
      }
    }
    __builtin_amdgcn_s_setprio(0);

    // ---- online softmax per t-group (lane owns t = trow + g*16 + l15) ----
    float mb[2];
#pragma unroll
    for (int g = 0; g < 2; ++g) {
      float a0 = fmaxf(fmaxf(sf[0][g][0], sf[0][g][1]), fmaxf(sf[0][g][2], sf[0][g][3]));
      float a1 = fmaxf(fmaxf(sf[1][g][0], sf[1][g][1]), fmaxf(sf[1][g][2], sf[1][g][3]));
      float a2 = fmaxf(fmaxf(sf[2][g][0], sf[2][g][1]), fmaxf(sf[2][g][2], sf[2][g][3]));
      float a3 = fmaxf(fmaxf(sf[3][g][0], sf[3][g][1]), fmaxf(sf[3][g][2], sf[3][g][3]));
      float m = fmaxf(fmaxf(a0, a1), fmaxf(a2, a3));
      m = fmaxf(m, __shfl_xor(m, 16));
      mb[g] = fmaxf(m, __shfl_xor(m, 32));
    }
    float dmax = fmaxf(mb[0] - m_run[0], mb[1] - m_run[1]);
    if (!__all(dmax <= 8.f)) {                    // T13 defer-max (both groups)
#pragma unroll
      for (int g = 0; g < 2; ++g) {
        float mn = fmaxf(m_run[g], mb[g]);
        float corr = __expf(m_run[g] - mn);
        m_run[g] = mn;
        l_run[g] *= corr;
#pragma unroll
        for (int cf = 0; cf < 4; ++cf)
#pragma unroll
          for (int i = 0; i < 4; ++i) oacc[cf][g][i] *= corr;
      }
    }
#pragma unroll
    for (int g = 0; g < 2; ++g) {
      char* PwRow = Pw + (g * 16 + l15) * 128;
      float sb = 0.f;
#pragma unroll
      for (int nf = 0; nf < 4; ++nf) {
        float p0 = __expf(sf[nf][g][0] - m_run[g]), p1 = __expf(sf[nf][g][1] - m_run[g]);
        float p2 = __expf(sf[nf][g][2] - m_run[g]), p3 = __expf(sf[nf][g][3] - m_run[g]);
        sb += (p0 + p1) + (p2 + p3);
        int off = nf * 32 + l4 * 8;
        *(bf16x4*)(PwRow + (off ^ rsw)) = (bf16x4){ (bf16)p0, (bf16)p1, (bf16)p2, (bf16)p3 };
      }
      sb += __shfl_xor(sb, 16);
      sb += __shfl_xor(sb, 32);
      l_run[g] += sb;
    }

    // ---- PV swapped: O^T += V * P, 16 MFMA (each vf feeds both groups) ----
    const char* Vb = (const char*)Vt[cur];
    __builtin_amdgcn_s_setprio(1);
#pragma unroll
    for (int kb = 0; kb < 2; ++kb) {
      bf16x8 pf0 = *(const bf16x8*)(Pw + l15 * 128 + ((kb * 64 + l4 * 16) ^ rsw));
      bf16x8 pf1 = *(const bf16x8*)(Pw + (16 + l15) * 128 + ((kb * 64 + l4 * 16) ^ rsw));
#pragma unroll
      for (int cf = 0; cf < 4; ++cf) {
        int rr = cf * 16 + l15;
        bf16x8 vf = *(const bf16x8*)(Vb + rr * 128 + ((kb * 64 + l4 * 16) ^ rsw));
        oacc[cf][0] = mfma16(vf, pf0, oacc[cf][0]);
        oacc[cf][1] = mfma16(vf, pf1, oacc[cf][1]);
      }
    }
    __builtin_amdgcn_s_setprio(0);
    __syncthreads();   // drains vmcnt(0): next tile staged & this tile's readers done
  }

#pragma unroll
  for (int g = 0; g < 2; ++g) {
    float rdiv = 1.f / l_run[g];
    int t = trow + g * 16 + l15;
#pragma unroll
    for (int cf = 0; cf < 4; ++cf) {
      bf16x4 ov = { (bf16)(oacc[cf][g][0] * rdiv), (bf16)(oacc[cf][g][1] * rdiv),
                    (bf16)(oacc[cf][g][2] * rdiv), (bf16)(oacc[cf][g][3] * rdiv) };
      *(bf16x4*)&aT[((size_t)b * 1024 + t) * 1024 + h * 64 + cf * 16 + l4 * 4] = ov;
    }
  }
}

extern "C" void kernel_launch(void* const* d_in, const int* in_sizes, int n_in,
                              void* d_out, int out_size, void* d_ws, size_t ws_size,
                              hipStream_t stream) {
  const float* x      = (const float*)d_in[0];
  const float* gw     = (const float*)d_in[1];
  const float* gb     = (const float*)d_in[2];
  const float* qkv_w  = (const float*)d_in[3];
  const float* qkv_b  = (const float*)d_in[4];
  const float* proj_w = (const float*)d_in[5];
  const float* proj_b = (const float*)d_in[6];
  float* out = (float*)d_out;

  char* ws = (char*)d_ws;
  bf16* wq_bf = (bf16*)(ws);                          //  6 MB: 3072x1024
  bf16* wp_bf = (bf16*)(ws + 6ll  * 1024 * 1024);     //  2 MB: 1024x1024
  bf16* xnT   = (bf16*)(ws + 8ll  * 1024 * 1024);     //  8 MB: [4][1024][1024]
  bf16* qkT   = (bf16*)(ws + 16ll * 1024 * 1024);     // 16 MB: [4][1024][2048] (q|k per head)
  bf16* vC    = (bf16*)(ws + 32ll * 1024 * 1024);     //  8 MB: [64][64][1024]
  bf16* aT    = (bf16*)(ws + 40ll * 1024 * 1024);     //  8 MB: [4][1024][1024]

  hipFuncSetAttribute(reinterpret_cast<const void*>(qkv_kernel),
                      hipFuncAttributeMaxDynamicSharedMemorySize, 114688);

  cvt2_kernel<<<dim3(4096), dim3(256), 0, stream>>>(qkv_w, wq_bf, proj_w, wp_bf);
  gn_kernel<<<dim3(512), dim3(512), 0, stream>>>(x, gw, gb, xnT);
  qkv_kernel<<<dim3(256), dim3(512), 114688, stream>>>(xnT, wq_bf, qkv_b, qkT, vC);
  attn_kernel<<<dim3(512), dim3(256), 0, stream>>>(qkT, vC, aT);
  gemm_kernel<1><<<dim3(8, 8, 4), dim3(256), 0, stream>>>(aT, wp_bf, proj_b, nullptr, nullptr, x, out);
}

// Round 9
// 108.400 us; speedup vs baseline: 1.0206x; 1.0206x over previous
//
#include <hip/hip_runtime.h>
#include <hip/hip_bf16.h>

typedef __bf16 bf16;
typedef __bf16 bf16x2 __attribute__((ext_vector_type(2)));
typedef __bf16 bf16x4 __attribute__((ext_vector_type(4)));
typedef __bf16 bf16x8 __attribute__((ext_vector_type(8)));
typedef float  f32x4  __attribute__((ext_vector_type(4)));

static __device__ __forceinline__ f32x4 mfma16(bf16x8 a, bf16x8 b, f32x4 c) {
  return __builtin_amdgcn_mfma_f32_16x16x32_bf16(a, b, c, 0, 0, 0);
}

static __device__ __forceinline__ void gload_lds16(const bf16* g, bf16* l) {
  __builtin_amdgcn_global_load_lds(
      (const __attribute__((address_space(1))) void*)g,
      (__attribute__((address_space(3))) void*)l, 16, 0, 0);
}

#define VMCNT0() asm volatile("s_waitcnt vmcnt(0)" ::: "memory")
#define BARRIER()                                        \
  do {                                                   \
    asm volatile("" ::: "memory");                       \
    __builtin_amdgcn_s_barrier();                        \
    asm volatile("" ::: "memory");                       \
  } while (0)

// ---------------- fp32 -> bf16 weight cast (both weights, one launch) ----------------
__global__ __launch_bounds__(256) void cvt2_kernel(const float* __restrict__ wa,
                                                   bf16* __restrict__ oa,
                                                   const float* __restrict__ wb,
                                                   bf16* __restrict__ ob) {
  int i = blockIdx.x * 256 + threadIdx.x;
  const int na4 = 3072 * 1024 / 4;
  const float* src; bf16* dst;
  if (i < na4) { src = wa; dst = oa; }
  else         { src = wb; dst = ob; i -= na4; }
  float4 v = ((const float4*)src)[i];
  bf16x4 o = { (bf16)v.x, (bf16)v.y, (bf16)v.z, (bf16)v.w };
  *(bf16x4*)(dst + 4ll * i) = o;
}

// ---------------- GroupNorm -> xnT (b, t, c) bf16 ----------------
__global__ __launch_bounds__(512) void gn_kernel(const float* __restrict__ x,
                                                 const float* __restrict__ w,
                                                 const float* __restrict__ bias,
                                                 bf16* __restrict__ xnT) {
  int id = blockIdx.x;
  int b = id >> 7, g = (id >> 2) & 31, qtr = id & 3;
  const float* xb = x + ((size_t)b * 1024 + g * 32) * 1024;   // 32 ch x 1024 t
  int tid = threadIdx.x;
  float s = 0.f, sq = 0.f;
  const float4* x4 = (const float4*)xb;
  for (int i = tid; i < 8192; i += 512) {
    float4 v = x4[i];
    s  += v.x + v.y + v.z + v.w;
    sq += v.x * v.x + v.y * v.y + v.z * v.z + v.w * v.w;
  }
#pragma unroll
  for (int off = 32; off; off >>= 1) { s += __shfl_down(s, off); sq += __shfl_down(sq, off); }
  __shared__ float red[16];
  int wv = tid >> 6;
  if ((tid & 63) == 0) { red[wv] = s; red[8 + wv] = sq; }
  __syncthreads();
  s = 0.f; sq = 0.f;
#pragma unroll
  for (int i = 0; i < 8; ++i) { s += red[i]; sq += red[8 + i]; }
  float mean = s * (1.f / 32768.f);
  float var  = sq * (1.f / 32768.f) - mean * mean;
  float rstd = rsqrtf(var + 1e-5f);

  __shared__ bf16 tile[64][36];
  int c = tid >> 4, q = tid & 15;              // load role: ch c, t-quad q
  int r = tid >> 3, q2 = tid & 7;              // store role: row r, ch-quad q2
  float wc = w[g * 32 + c] * rstd;
  float fb = bias[g * 32 + c] - mean * wc;
  for (int t0 = qtr * 256; t0 < qtr * 256 + 256; t0 += 64) {
    float4 v = *(const float4*)(xb + (size_t)c * 1024 + t0 + q * 4);
    tile[q * 4 + 0][c] = (bf16)(v.x * wc + fb);
    tile[q * 4 + 1][c] = (bf16)(v.y * wc + fb);
    tile[q * 4 + 2][c] = (bf16)(v.z * wc + fb);
    tile[q * 4 + 3][c] = (bf16)(v.w * wc + fb);
    __syncthreads();
    *(bf16x4*)&xnT[((size_t)b * 1024 + t0 + r) * 1024 + g * 32 + q2 * 4] =
        *(bf16x4*)&tile[r][q2 * 4];
    __syncthreads();
  }
}

// ---------------- QKV GEMM: 256x192x64, double-buffered, 1 barrier/tile ----------------
// Free-slip schedule: per K-tile {ds_read B+A0 | stage A(t+1) | MFMA0 |
// ds_read A1 | stage B(t+1) | MFMA1 | vmcnt(0) | barrier}. Compiler emits
// fine-grained lgkmcnt; waves desync within the tile to overlap LDS vs MFMA.
__global__ __launch_bounds__(512, 1) void qkv_kernel(
    const bf16* __restrict__ A, const bf16* __restrict__ Bw,
    const float* __restrict__ bias,
    bf16* __restrict__ qkT, bf16* __restrict__ vC) {
  extern __shared__ __align__(16) bf16 smem[];
  // bytes: A(d,h) @ d*32768 + h*16384 (128x64 each); B(d) @ 65536 + d*24576 (192x64)

  int tid = threadIdx.x, wid = tid >> 6, lane = tid & 63;
  int l15 = lane & 15, l4 = lane >> 4;
  int wr = wid >> 2, wc = wid & 3;
  int rsw = (l15 & 7) << 4;

  int sid = (blockIdx.x & 7) * 32 + (blockIdx.x >> 3);   // XCD chunk swizzle (256%8==0)
  int bx = sid & 15, by = (sid >> 4) & 3, z = sid >> 6;
  int m0 = by * 256, n0 = bx * 192;
  const bf16* Ab = A + (size_t)z * 1024 * 1024 + (size_t)m0 * 1024;
  const bf16* Bb = Bw + (size_t)n0 * 1024;

  int srow = tid >> 3;                    // 0..63
  int csw  = (tid & 7) ^ (srow & 7);      // pre-swizzled source chunk
  auto stageA = [&](int d, int h, int kt) {
    bf16* dst = smem + d * 16384 + h * 8192;
    const bf16* src = Ab + (size_t)(h * 128) * 1024 + kt * 64 + csw * 8;
#pragma unroll
    for (int L = 0; L < 2; ++L)
      gload_lds16(src + (size_t)(L * 64 + srow) * 1024, dst + (L * 512 + wid * 64) * 8);
  };
  auto stageB = [&](int d, int kt) {
    bf16* dst = smem + 32768 + d * 12288;
    const bf16* src = Bb + kt * 64 + csw * 8;
#pragma unroll
    for (int L = 0; L < 3; ++L)
      gload_lds16(src + (size_t)(L * 64 + srow) * 1024, dst + (L * 512 + wid * 64) * 8);
  };

  f32x4 acc[8][3] = {};

  stageA(0, 0, 0); stageA(0, 1, 0); stageB(0, 0);
  VMCNT0();
  BARRIER();

  for (int t = 0; t < 16; ++t) {
    int d = t & 1;
    const char* Ab8 = (const char*)smem + d * 32768 + wr * 16384;
    const char* Bb8 = (const char*)smem + 65536 + d * 24576;

    // B frags (held all tile) + A rows 0..63; stage A(t+1) into d^1
    bf16x8 bfr[3][2], af[4][2];
#pragma unroll
    for (int ni = 0; ni < 3; ++ni) {
      int rb = (wc * 48 + ni * 16 + l15) * 128;
#pragma unroll
      for (int kk = 0; kk < 2; ++kk)
        bfr[ni][kk] = *(const bf16x8*)(Bb8 + rb + ((kk * 64 + l4 * 16) ^ rsw));
    }
#pragma unroll
    for (int mi = 0; mi < 4; ++mi) {
      int rb = (mi * 16 + l15) * 128;
#pragma unroll
      for (int kk = 0; kk < 2; ++kk)
        af[mi][kk] = *(const bf16x8*)(Ab8 + rb + ((kk * 64 + l4 * 16) ^ rsw));
    }
    if (t < 15) { stageA(d ^ 1, 0, t + 1); stageA(d ^ 1, 1, t + 1); }
#pragma unroll
    for (int mi = 0; mi < 4; ++mi)
#pragma unroll
      for (int ni = 0; ni < 3; ++ni)
#pragma unroll
        for (int kk = 0; kk < 2; ++kk)
          acc[mi][ni] = mfma16(af[mi][kk], bfr[ni][kk], acc[mi][ni]);

    // A rows 64..127; stage B(t+1)
#pragma unroll
    for (int mi = 0; mi < 4; ++mi) {
      int rb = ((4 + mi) * 16 + l15) * 128;
#pragma unroll
      for (int kk = 0; kk < 2; ++kk)
        af[mi][kk] = *(const bf16x8*)(Ab8 + rb + ((kk * 64 + l4 * 16) ^ rsw));
    }
    if (t < 15) stageB(d ^ 1, t + 1);
#pragma unroll
    for (int mi = 0; mi < 4; ++mi)
#pragma unroll
      for (int ni = 0; ni < 3; ++ni)
#pragma unroll
        for (int kk = 0; kk < 2; ++kk)
          acc[4 + mi][ni] = mfma16(af[mi][kk], bfr[ni][kk], acc[4 + mi][ni]);

    VMCNT0();    // d^1 fully staged (issued this tile) before anyone reads it
    BARRIER();   // + all waves done reading d before next tile stages into it
  }

  // ---- epilogue: bias, q/k scale, split write (single head h = bx) ----
  const float scale = 0.35355339059327373f;   // 64^-0.25
  int h = bx;
#pragma unroll
  for (int ni = 0; ni < 3; ++ni) {
    int oin = wc * 48 + ni * 16;              // 0..176, wave-uniform
    float bv = bias[n0 + oin + l15];
#pragma unroll
    for (int mi = 0; mi < 8; ++mi) {
      int tb = m0 + wr * 128 + mi * 16 + l4 * 4;
      f32x4 v = acc[mi][ni];
      if (oin < 128) {                        // q|k -> qkT[b][t][h*128 + oin]
#pragma unroll
        for (int i = 0; i < 4; ++i)
          qkT[((size_t)z * 1024 + tb + i) * 2048 + h * 128 + oin + l15] =
              (bf16)((v[i] + bv) * scale);
      } else {                                // v -> vC[(b*16+h)][c][t]
        bf16x4 st = { (bf16)(v[0] + bv), (bf16)(v[1] + bv),
                      (bf16)(v[2] + bv), (bf16)(v[3] + bv) };
        *(bf16x4*)&vC[(((size_t)z * 16 + h) * 64 + (oin - 128 + l15)) * 1024 + tb] = st;
      }
    }
  }
}

// ---------------- 128x128x32 bf16 MFMA GEMM (proj: bias + residual) ----------------
template <int MODE>
__global__ __launch_bounds__(256) void gemm_kernel(
    const bf16* __restrict__ A, const bf16* __restrict__ Bw,
    const float* __restrict__ bias,
    bf16* __restrict__ qkT, bf16* __restrict__ vC,
    const float* __restrict__ xres, float* __restrict__ out) {
  __shared__ bf16 At[128 * 32];
  __shared__ bf16 Bt[128 * 32];
  int tid = threadIdx.x;
  int wid = tid >> 6, lane = tid & 63;
  int l15 = lane & 15, l4 = lane >> 4;
  int wm = wid >> 1, wn = wid & 1;
  int z = blockIdx.z;
  int m0 = blockIdx.y * 128, n0 = blockIdx.x * 128;
  const bf16* Ab = A + (size_t)z * 1024 * 1024 + (size_t)m0 * 1024;
  const bf16* Bb = Bw + (size_t)n0 * 1024;

  f32x4 acc[4][4] = {};

  for (int k0 = 0; k0 < 1024; k0 += 32) {
#pragma unroll
    for (int j = 0; j < 2; ++j) {
      int slot = j * 256 + tid;
      int row  = slot >> 2;
      int ck   = (slot & 3) ^ ((row >> 1) & 3);   // pre-swizzled source chunk
      gload_lds16(Ab + (size_t)row * 1024 + k0 + ck * 8, At + (size_t)(j * 256 + wid * 64) * 8);
      gload_lds16(Bb + (size_t)row * 1024 + k0 + ck * 8, Bt + (size_t)(j * 256 + wid * 64) * 8);
    }
    __syncthreads();
    bf16x8 af[4], bfr[4];
#pragma unroll
    for (int mi = 0; mi < 4; ++mi) {
      int row = wm * 64 + mi * 16 + l15;
      int ck  = l4 ^ ((row >> 1) & 3);
      af[mi] = *(const bf16x8*)(At + row * 32 + ck * 8);
    }
#pragma unroll
    for (int nf = 0; nf < 4; ++nf) {
      int row = wn * 64 + nf * 16 + l15;
      int ck  = l4 ^ ((row >> 1) & 3);
      bfr[nf] = *(const bf16x8*)(Bt + row * 32 + ck * 8);
    }
#pragma unroll
    for (int mi = 0; mi < 4; ++mi)
#pragma unroll
      for (int nf = 0; nf < 4; ++nf)
        acc[mi][nf] = mfma16(af[mi], bfr[nf], acc[mi][nf]);
    __syncthreads();
  }

  if (MODE == 1) {
#pragma unroll
    for (int nf = 0; nf < 4; ++nf) {
      int o = n0 + wn * 64 + nf * 16 + l15;
      float bv = bias[o];
#pragma unroll
      for (int mi = 0; mi < 4; ++mi) {
        int tb = m0 + wm * 64 + mi * 16 + l4 * 4;
        size_t base = ((size_t)z * 1024 + o) * 1024 + tb;
        float4 xr = *(const float4*)(xres + base);
        f32x4 v = acc[mi][nf];
        float4 ov = { xr.x + v[0] + bv, xr.y + v[1] + bv,
                      xr.z + v[2] + bv, xr.w + v[3] + bv };
        *(float4*)(out + base) = ov;
      }
    }
  }
}

// ---------------- flash attention v4: 8 waves, 128 t-rows/block ----------------
__global__ __launch_bounds__(512, 4) void attn_kernel(const bf16* __restrict__ qkT,
                                                      const bf16* __restrict__ vC,
                                                      bf16* __restrict__ aT) {
  __shared__ __align__(16) bf16 Kt[2][64 * 64];   // [buf][s][d] swizzled, 16 KB
  __shared__ __align__(16) bf16 Vt[2][64 * 64];   // [buf][c][s] swizzled, 16 KB
  __shared__ __align__(16) bf16 Pt[8][16 * 64];   // per-wave P[t][s], swizzled, 16 KB

  int id = blockIdx.x;
  int sid = (id & 7) * 64 + (id >> 3);            // bijective XCD swizzle (512 % 8 == 0)
  int head = sid >> 3, tblk = sid & 7;
  int b = head >> 4, h = head & 15;
  int t0 = tblk * 128;
  int tid = threadIdx.x, wid = tid >> 6, lane = tid & 63;
  int l15 = lane & 15, l4 = lane >> 4;
  int trow = t0 + wid * 16;

  const bf16* kbase = qkT + (size_t)b * 1024 * 2048 + h * 128 + 64;
  const bf16* vbase = vC + (size_t)(b * 16 + h) * 64 * 1024;
  char* Pw = (char*)Pt[wid];
  int rsw = (l15 & 7) << 4;                        // row-XOR for P (row = l15)
  char* PwRow = Pw + l15 * 128;

  // Q fragments (read once); B-operand layout: row=t=l15, k=l4*8+j
  const bf16* qrow = qkT + ((size_t)b * 1024 + trow + l15) * 2048 + h * 128;
  bf16x8 qf[2];
#pragma unroll
  for (int kb = 0; kb < 2; ++kb) qf[kb] = *(const bf16x8*)(qrow + kb * 32 + l4 * 8);

  // stage tile st into buffer buf: wave wid owns 8-row group wid of K and V
  int rl = lane >> 3;                              // row within 8-row group
  int scol = (((lane & 7) * 16) ^ (rl << 4)) >> 1; // element col, swizzle folded in
  int r8 = wid * 8 + rl;
  auto stage = [&](int buf, int st) {
    int s0 = st * 64;
    gload_lds16(kbase + (size_t)(s0 + r8) * 2048 + scol, &Kt[buf][wid * 512]);
    gload_lds16(vbase + (size_t)r8 * 1024 + s0 + scol, &Vt[buf][wid * 512]);
  };

  float m_run = -1e30f, l_run = 0.f;
  f32x4 oacc[4] = {};                              // O^T[c][t]: col t=l15, rows c

  stage(0, 0);
  __syncthreads();

  for (int st = 0; st < 16; ++st) {
    int cur = st & 1;
    if (st < 15) stage(cur ^ 1, st + 1);

    // ---- QK^T swapped: S^T[s][t], 8 MFMA ----
    const char* Kb = (const char*)Kt[cur];
    f32x4 sf[4];
#pragma unroll
    for (int nf = 0; nf < 4; ++nf) sf[nf] = (f32x4){0.f, 0.f, 0.f, 0.f};
    __builtin_amdgcn_s_setprio(1);
#pragma unroll
    for (int nf = 0; nf < 4; ++nf) {
      int rr = nf * 16 + l15;                      // A-frag row = s
#pragma unroll
      for (int kb = 0; kb < 2; ++kb) {
        bf16x8 kf = *(const bf16x8*)(Kb + rr * 128 + ((kb * 64 + l4 * 16) ^ rsw));
        sf[nf] = mfma16(kf, qf[kb], sf[nf]);
      }
    }
    __builtin_amdgcn_s_setprio(0);

    // ---- online softmax: lane owns t=l15, s = nf*16 + l4*4 + i ----
    float mb;
    {
      float a0 = fmaxf(fmaxf(sf[0][0], sf[0][1]), fmaxf(sf[0][2], sf[0][3]));
      float a1 = fmaxf(fmaxf(sf[1][0], sf[1][1]), fmaxf(sf[1][2], sf[1][3]));
      float a2 = fmaxf(fmaxf(sf[2][0], sf[2][1]), fmaxf(sf[2][2], sf[2][3]));
      float a3 = fmaxf(fmaxf(sf[3][0], sf[3][1]), fmaxf(sf[3][2], sf[3][3]));
      mb = fmaxf(fmaxf(a0, a1), fmaxf(a2, a3));
    }
    mb = fmaxf(mb, __shfl_xor(mb, 16));
    mb = fmaxf(mb, __shfl_xor(mb, 32));
    if (!__all(mb - m_run <= 8.f)) {               // T13 defer-max
      float mn = fmaxf(m_run, mb);
      float corr = __expf(m_run - mn);
      m_run = mn;
      l_run *= corr;
#pragma unroll
      for (int cf = 0; cf < 4; ++cf)
#pragma unroll
        for (int i = 0; i < 4; ++i) oacc[cf][i] *= corr;
    }
    float sb = 0.f;
#pragma unroll
    for (int nf = 0; nf < 4; ++nf) {
      float p0 = __expf(sf[nf][0] - m_run), p1 = __expf(sf[nf][1] - m_run);
      float p2 = __expf(sf[nf][2] - m_run), p3 = __expf(sf[nf][3] - m_run);
      sb += (p0 + p1) + (p2 + p3);
      int off = nf * 32 + l4 * 8;                  // 8-aligned; rsw is 16B-granular
      *(bf16x4*)(PwRow + (off ^ rsw)) = (bf16x4){ (bf16)p0, (bf16)p1, (bf16)p2, (bf16)p3 };
    }
    sb += __shfl_xor(sb, 16);
    sb += __shfl_xor(sb, 32);
    l_run += sb;

    // ---- PV swapped: O^T += V * P, 8 MFMA ----
    const char* Vb = (const char*)Vt[cur];
    __builtin_amdgcn_s_setprio(1);
#pragma unroll
    for (int kb = 0; kb < 2; ++kb) {
      bf16x8 pf = *(const bf16x8*)(Pw + l15 * 128 + ((kb * 64 + l4 * 16) ^ rsw));
#pragma unroll
      for (int cf = 0; cf < 4; ++cf) {
        int rr = cf * 16 + l15;                    // A-frag row = c
        bf16x8 vf = *(const bf16x8*)(Vb + rr * 128 + ((kb * 64 + l4 * 16) ^ rsw));
        oacc[cf] = mfma16(vf, pf, oacc[cf]);
      }
    }
    __builtin_amdgcn_s_setprio(0);
    __syncthreads();   // drains vmcnt(0): next tile staged & this tile's readers done
  }

  float rdiv = 1.f / l_run;                        // lane-local (t = l15)
  int t = trow + l15;
#pragma unroll
  for (int cf = 0; cf < 4; ++cf) {
    bf16x4 ov = { (bf16)(oacc[cf][0] * rdiv), (bf16)(oacc[cf][1] * rdiv),
                  (bf16)(oacc[cf][2] * rdiv), (bf16)(oacc[cf][3] * rdiv) };
    *(bf16x4*)&aT[((size_t)b * 1024 + t) * 1024 + h * 64 + cf * 16 + l4 * 4] = ov;
  }
}

extern "C" void kernel_launch(void* const* d_in, const int* in_sizes, int n_in,
                              void* d_out, int out_size, void* d_ws, size_t ws_size,
                              hipStream_t stream) {
  const float* x      = (const float*)d_in[0];
  const float* gw     = (const float*)d_in[1];
  const float* gb     = (const float*)d_in[2];
  const float* qkv_w  = (const float*)d_in[3];
  const float* qkv_b  = (const float*)d_in[4];
  const float* proj_w = (const float*)d_in[5];
  const float* proj_b = (const float*)d_in[6];
  float* out = (float*)d_out;

  char* ws = (char*)d_ws;
  bf16* wq_bf = (bf16*)(ws);                          //  6 MB: 3072x1024
  bf16* wp_bf = (bf16*)(ws + 6ll  * 1024 * 1024);     //  2 MB: 1024x1024
  bf16* xnT   = (bf16*)(ws + 8ll  * 1024 * 1024);     //  8 MB: [4][1024][1024]
  bf16* qkT   = (bf16*)(ws + 16ll * 1024 * 1024);     // 16 MB: [4][1024][2048] (q|k per head)
  bf16* vC    = (bf16*)(ws + 32ll * 1024 * 1024);     //  8 MB: [64][64][1024]
  bf16* aT    = (bf16*)(ws + 40ll * 1024 * 1024);     //  8 MB: [4][1024][1024]

  hipFuncSetAttribute(reinterpret_cast<const void*>(qkv_kernel),
                      hipFuncAttributeMaxDynamicSharedMemorySize, 114688);

  cvt2_kernel<<<dim3(4096), dim3(256), 0, stream>>>(qkv_w, wq_bf, proj_w, wp_bf);
  gn_kernel<<<dim3(512), dim3(512), 0, stream>>>(x, gw, gb, xnT);
  qkv_kernel<<<dim3(256), dim3(512), 114688, stream>>>(xnT, wq_bf, qkv_b, qkT, vC);
  attn_kernel<<<dim3(512), dim3(512), 0, stream>>>(qkT, vC, aT);
  gemm_kernel<1><<<dim3(8, 8, 4), dim3(256), 0, stream>>>(aT, wp_bf, proj_b, nullptr, nullptr, x, out);
}

// Round 10
// 107.095 us; speedup vs baseline: 1.0330x; 1.0122x over previous
//
#include <hip/hip_runtime.h>
#include <hip/hip_bf16.h>

typedef __bf16 bf16;
typedef __bf16 bf16x2 __attribute__((ext_vector_type(2)));
typedef __bf16 bf16x4 __attribute__((ext_vector_type(4)));
typedef __bf16 bf16x8 __attribute__((ext_vector_type(8)));
typedef float  f32x4  __attribute__((ext_vector_type(4)));

static __device__ __forceinline__ f32x4 mfma16(bf16x8 a, bf16x8 b, f32x4 c) {
  return __builtin_amdgcn_mfma_f32_16x16x32_bf16(a, b, c, 0, 0, 0);
}

static __device__ __forceinline__ void gload_lds16(const bf16* g, bf16* l) {
  __builtin_amdgcn_global_load_lds(
      (const __attribute__((address_space(1))) void*)g,
      (__attribute__((address_space(3))) void*)l, 16, 0, 0);
}

#define VMCNT0() asm volatile("s_waitcnt vmcnt(0)" ::: "memory")
#define VMCNT4() asm volatile("s_waitcnt vmcnt(4)" ::: "memory")
#define BARRIER()                                        \
  do {                                                   \
    asm volatile("" ::: "memory");                       \
    __builtin_amdgcn_s_barrier();                        \
    asm volatile("" ::: "memory");                       \
  } while (0)

// ---------------- fp32 -> bf16 weight cast (both weights, one launch) ----------------
__global__ __launch_bounds__(256) void cvt2_kernel(const float* __restrict__ wa,
                                                   bf16* __restrict__ oa,
                                                   const float* __restrict__ wb,
                                                   bf16* __restrict__ ob) {
  int i = blockIdx.x * 256 + threadIdx.x;
  const int na4 = 3072 * 1024 / 4;
  const float* src; bf16* dst;
  if (i < na4) { src = wa; dst = oa; }
  else         { src = wb; dst = ob; i -= na4; }
  float4 v = ((const float4*)src)[i];
  bf16x4 o = { (bf16)v.x, (bf16)v.y, (bf16)v.z, (bf16)v.w };
  *(bf16x4*)(dst + 4ll * i) = o;
}

// ---------------- GroupNorm -> xnT (b, t, c) bf16 ----------------
__global__ __launch_bounds__(512) void gn_kernel(const float* __restrict__ x,
                                                 const float* __restrict__ w,
                                                 const float* __restrict__ bias,
                                                 bf16* __restrict__ xnT) {
  int id = blockIdx.x;
  int b = id >> 7, g = (id >> 2) & 31, qtr = id & 3;
  const float* xb = x + ((size_t)b * 1024 + g * 32) * 1024;   // 32 ch x 1024 t
  int tid = threadIdx.x;
  float s = 0.f, sq = 0.f;
  const float4* x4 = (const float4*)xb;
  for (int i = tid; i < 8192; i += 512) {
    float4 v = x4[i];
    s  += v.x + v.y + v.z + v.w;
    sq += v.x * v.x + v.y * v.y + v.z * v.z + v.w * v.w;
  }
#pragma unroll
  for (int off = 32; off; off >>= 1) { s += __shfl_down(s, off); sq += __shfl_down(sq, off); }
  __shared__ float red[16];
  int wv = tid >> 6;
  if ((tid & 63) == 0) { red[wv] = s; red[8 + wv] = sq; }
  __syncthreads();
  s = 0.f; sq = 0.f;
#pragma unroll
  for (int i = 0; i < 8; ++i) { s += red[i]; sq += red[8 + i]; }
  float mean = s * (1.f / 32768.f);
  float var  = sq * (1.f / 32768.f) - mean * mean;
  float rstd = rsqrtf(var + 1e-5f);

  __shared__ bf16 tile[64][36];
  int c = tid >> 4, q = tid & 15;              // load role: ch c, t-quad q
  int r = tid >> 3, q2 = tid & 7;              // store role: row r, ch-quad q2
  float wc = w[g * 32 + c] * rstd;
  float fb = bias[g * 32 + c] - mean * wc;
  for (int t0 = qtr * 256; t0 < qtr * 256 + 256; t0 += 64) {
    float4 v = *(const float4*)(xb + (size_t)c * 1024 + t0 + q * 4);
    tile[q * 4 + 0][c] = (bf16)(v.x * wc + fb);
    tile[q * 4 + 1][c] = (bf16)(v.y * wc + fb);
    tile[q * 4 + 2][c] = (bf16)(v.z * wc + fb);
    tile[q * 4 + 3][c] = (bf16)(v.w * wc + fb);
    __syncthreads();
    *(bf16x4*)&xnT[((size_t)b * 1024 + t0 + r) * 1024 + g * 32 + q2 * 4] =
        *(bf16x4*)&tile[r][q2 * 4];
    __syncthreads();
  }
}

// ---------------- QKV GEMM: 256x192x64, T4 counted-vmcnt pipeline ----------------
// A triple-buffered (3x32KB), B double-buffered (2x24KB) = 144 KB LDS.
// Per tile t: issue stageB(t+1), stageA(t+2) [A LAST]; compute; then
// s_waitcnt vmcnt(4) (allow A(t+2) in flight; A(t+1)+B(t+1) guaranteed done).
// Never drains to 0 in the main loop (m218: +38-73% vs drain-0).
__global__ __launch_bounds__(512, 1) void qkv_kernel(
    const bf16* __restrict__ A, const bf16* __restrict__ Bw,
    const float* __restrict__ bias,
    bf16* __restrict__ qkT, bf16* __restrict__ vC) {
  extern __shared__ __align__(16) bf16 smem[];
  // elems: A(d) @ d*16384 (256x64 each, d=0..2); B(d) @ 49152 + d*12288 (192x64)

  int tid = threadIdx.x, wid = tid >> 6, lane = tid & 63;
  int l15 = lane & 15, l4 = lane >> 4;
  int wr = wid >> 2, wc = wid & 3;
  int rsw = (l15 & 7) << 4;

  int sid = (blockIdx.x & 7) * 32 + (blockIdx.x >> 3);   // XCD chunk swizzle (256%8==0)
  int bx = sid & 15, by = (sid >> 4) & 3, z = sid >> 6;
  int m0 = by * 256, n0 = bx * 192;
  const bf16* Ab = A + (size_t)z * 1024 * 1024 + (size_t)m0 * 1024;
  const bf16* Bb = Bw + (size_t)n0 * 1024;

  int srow = tid >> 3;                    // 0..63
  int csw  = (tid & 7) ^ (srow & 7);      // pre-swizzled source chunk
  auto stageA = [&](int d, int kt) {      // 4 gloads/thread
    bf16* dst = smem + d * 16384;
    const bf16* src = Ab + kt * 64 + csw * 8;
#pragma unroll
    for (int hh = 0; hh < 2; ++hh)
#pragma unroll
      for (int L = 0; L < 2; ++L)
        gload_lds16(src + (size_t)(hh * 128 + L * 64 + srow) * 1024,
                    dst + hh * 8192 + (L * 512 + wid * 64) * 8);
  };
  auto stageB = [&](int d, int kt) {      // 3 gloads/thread
    bf16* dst = smem + 49152 + d * 12288;
    const bf16* src = Bb + kt * 64 + csw * 8;
#pragma unroll
    for (int L = 0; L < 3; ++L)
      gload_lds16(src + (size_t)(L * 64 + srow) * 1024, dst + (L * 512 + wid * 64) * 8);
  };

  f32x4 acc[8][3] = {};

  auto compute = [&](int ta, int tb) {
    const char* Ab8 = (const char*)smem + ta * 32768 + wr * 16384;
    const char* Bb8 = (const char*)smem + 98304 + tb * 24576;
    bf16x8 bfr[3][2], af[4][2];
#pragma unroll
    for (int ni = 0; ni < 3; ++ni) {
      int rb = (wc * 48 + ni * 16 + l15) * 128;
#pragma unroll
      for (int kk = 0; kk < 2; ++kk)
        bfr[ni][kk] = *(const bf16x8*)(Bb8 + rb + ((kk * 64 + l4 * 16) ^ rsw));
    }
#pragma unroll
    for (int mi = 0; mi < 4; ++mi) {
      int rb = (mi * 16 + l15) * 128;
#pragma unroll
      for (int kk = 0; kk < 2; ++kk)
        af[mi][kk] = *(const bf16x8*)(Ab8 + rb + ((kk * 64 + l4 * 16) ^ rsw));
    }
#pragma unroll
    for (int mi = 0; mi < 4; ++mi)
#pragma unroll
      for (int ni = 0; ni < 3; ++ni)
#pragma unroll
        for (int kk = 0; kk < 2; ++kk)
          acc[mi][ni] = mfma16(af[mi][kk], bfr[ni][kk], acc[mi][ni]);
#pragma unroll
    for (int mi = 0; mi < 4; ++mi) {
      int rb = ((4 + mi) * 16 + l15) * 128;
#pragma unroll
      for (int kk = 0; kk < 2; ++kk)
        af[mi][kk] = *(const bf16x8*)(Ab8 + rb + ((kk * 64 + l4 * 16) ^ rsw));
    }
#pragma unroll
    for (int mi = 0; mi < 4; ++mi)
#pragma unroll
      for (int ni = 0; ni < 3; ++ni)
#pragma unroll
        for (int kk = 0; kk < 2; ++kk)
          acc[4 + mi][ni] = mfma16(af[mi][kk], bfr[ni][kk], acc[4 + mi][ni]);
  };

  // prologue: A(0), B(0), A(1) in flight; wait all but newest 4 (=A(1))
  stageA(0, 0); stageB(0, 0); stageA(1, 1);
  VMCNT4();
  BARRIER();

  for (int t = 0; t < 14; ++t) {
    stageB((t + 1) & 1, t + 1);       // issued first (must complete by tile end)
    stageA((t + 2) % 3, t + 2);       // issued LAST (allowed to stay in flight)
    compute(t % 3, t & 1);
    VMCNT4();    // A(t+1), B(t+1) done; A(t+2)'s 4 loads may remain outstanding
    BARRIER();   // all waves done reading bufs t before t+1 stages overwrite
  }
  // tile 14: stage B(15) only; must drain fully (A(15) has no successor)
  stageB(1, 15);
  compute(2, 0);
  VMCNT0();
  BARRIER();
  // tile 15: no stages
  compute(0, 1);

  // ---- epilogue: bias, q/k scale, split write (single head h = bx) ----
  const float scale = 0.35355339059327373f;   // 64^-0.25
  int h = bx;
#pragma unroll
  for (int ni = 0; ni < 3; ++ni) {
    int oin = wc * 48 + ni * 16;              // 0..176, wave-uniform
    float bv = bias[n0 + oin + l15];
#pragma unroll
    for (int mi = 0; mi < 8; ++mi) {
      int tb = m0 + wr * 128 + mi * 16 + l4 * 4;
      f32x4 v = acc[mi][ni];
      if (oin < 128) {                        // q|k -> qkT[b][t][h*128 + oin]
#pragma unroll
        for (int i = 0; i < 4; ++i)
          qkT[((size_t)z * 1024 + tb + i) * 2048 + h * 128 + oin + l15] =
              (bf16)((v[i] + bv) * scale);
      } else {                                // v -> vC[(b*16+h)][c][t]
        bf16x4 st = { (bf16)(v[0] + bv), (bf16)(v[1] + bv),
                      (bf16)(v[2] + bv), (bf16)(v[3] + bv) };
        *(bf16x4*)&vC[(((size_t)z * 16 + h) * 64 + (oin - 128 + l15)) * 1024 + tb] = st;
      }
    }
  }
}

// ---------------- 128x128x32 bf16 MFMA GEMM (proj: bias + residual) ----------------
template <int MODE>
__global__ __launch_bounds__(256) void gemm_kernel(
    const bf16* __restrict__ A, const bf16* __restrict__ Bw,
    const float* __restrict__ bias,
    bf16* __restrict__ qkT, bf16* __restrict__ vC,
    const float* __restrict__ xres, float* __restrict__ out) {
  __shared__ bf16 At[128 * 32];
  __shared__ bf16 Bt[128 * 32];
  int tid = threadIdx.x;
  int wid = tid >> 6, lane = tid & 63;
  int l15 = lane & 15, l4 = lane >> 4;
  int wm = wid >> 1, wn = wid & 1;
  int z = blockIdx.z;
  int m0 = blockIdx.y * 128, n0 = blockIdx.x * 128;
  const bf16* Ab = A + (size_t)z * 1024 * 1024 + (size_t)m0 * 1024;
  const bf16* Bb = Bw + (size_t)n0 * 1024;

  f32x4 acc[4][4] = {};

  for (int k0 = 0; k0 < 1024; k0 += 32) {
#pragma unroll
    for (int j = 0; j < 2; ++j) {
      int slot = j * 256 + tid;
      int row  = slot >> 2;
      int ck   = (slot & 3) ^ ((row >> 1) & 3);   // pre-swizzled source chunk
      gload_lds16(Ab + (size_t)row * 1024 + k0 + ck * 8, At + (size_t)(j * 256 + wid * 64) * 8);
      gload_lds16(Bb + (size_t)row * 1024 + k0 + ck * 8, Bt + (size_t)(j * 256 + wid * 64) * 8);
    }
    __syncthreads();
    bf16x8 af[4], bfr[4];
#pragma unroll
    for (int mi = 0; mi < 4; ++mi) {
      int row = wm * 64 + mi * 16 + l15;
      int ck  = l4 ^ ((row >> 1) & 3);
      af[mi] = *(const bf16x8*)(At + row * 32 + ck * 8);
    }
#pragma unroll
    for (int nf = 0; nf < 4; ++nf) {
      int row = wn * 64 + nf * 16 + l15;
      int ck  = l4 ^ ((row >> 1) & 3);
      bfr[nf] = *(const bf16x8*)(Bt + row * 32 + ck * 8);
    }
#pragma unroll
    for (int mi = 0; mi < 4; ++mi)
#pragma unroll
      for (int nf = 0; nf < 4; ++nf)
        acc[mi][nf] = mfma16(af[mi], bfr[nf], acc[mi][nf]);
    __syncthreads();
  }

  if (MODE == 1) {
#pragma unroll
    for (int nf = 0; nf < 4; ++nf) {
      int o = n0 + wn * 64 + nf * 16 + l15;
      float bv = bias[o];
#pragma unroll
      for (int mi = 0; mi < 4; ++mi) {
        int tb = m0 + wm * 64 + mi * 16 + l4 * 4;
        size_t base = ((size_t)z * 1024 + o) * 1024 + tb;
        float4 xr = *(const float4*)(xres + base);
        f32x4 v = acc[mi][nf];
        float4 ov = { xr.x + v[0] + bv, xr.y + v[1] + bv,
                      xr.z + v[2] + bv, xr.w + v[3] + bv };
        *(float4*)(out + base) = ov;
      }
    }
  }
}

// ---------------- flash attention v4: 8 waves, 128 t-rows/block ----------------
__global__ __launch_bounds__(512, 4) void attn_kernel(const bf16* __restrict__ qkT,
                                                      const bf16* __restrict__ vC,
                                                      bf16* __restrict__ aT) {
  __shared__ __align__(16) bf16 Kt[2][64 * 64];   // [buf][s][d] swizzled, 16 KB
  __shared__ __align__(16) bf16 Vt[2][64 * 64];   // [buf][c][s] swizzled, 16 KB
  __shared__ __align__(16) bf16 Pt[8][16 * 64];   // per-wave P[t][s], swizzled, 16 KB

  int id = blockIdx.x;
  int sid = (id & 7) * 64 + (id >> 3);            // bijective XCD swizzle (512 % 8 == 0)
  int head = sid >> 3, tblk = sid & 7;
  int b = head >> 4, h = head & 15;
  int t0 = tblk * 128;
  int tid = threadIdx.x, wid = tid >> 6, lane = tid & 63;
  int l15 = lane & 15, l4 = lane >> 4;
  int trow = t0 + wid * 16;

  const bf16* kbase = qkT + (size_t)b * 1024 * 2048 + h * 128 + 64;
  const bf16* vbase = vC + (size_t)(b * 16 + h) * 64 * 1024;
  char* Pw = (char*)Pt[wid];
  int rsw = (l15 & 7) << 4;                        // row-XOR for P (row = l15)
  char* PwRow = Pw + l15 * 128;

  // Q fragments (read once); B-operand layout: row=t=l15, k=l4*8+j
  const bf16* qrow = qkT + ((size_t)b * 1024 + trow + l15) * 2048 + h * 128;
  bf16x8 qf[2];
#pragma unroll
  for (int kb = 0; kb < 2; ++kb) qf[kb] = *(const bf16x8*)(qrow + kb * 32 + l4 * 8);

  // stage tile st into buffer buf: wave wid owns 8-row group wid of K and V
  int rl = lane >> 3;                              // row within 8-row group
  int scol = (((lane & 7) * 16) ^ (rl << 4)) >> 1; // element col, swizzle folded in
  int r8 = wid * 8 + rl;
  auto stage = [&](int buf, int st) {
    int s0 = st * 64;
    gload_lds16(kbase + (size_t)(s0 + r8) * 2048 + scol, &Kt[buf][wid * 512]);
    gload_lds16(vbase + (size_t)r8 * 1024 + s0 + scol, &Vt[buf][wid * 512]);
  };

  float m_run = -1e30f, l_run = 0.f;
  f32x4 oacc[4] = {};                              // O^T[c][t]: col t=l15, rows c

  stage(0, 0);
  __syncthreads();

  for (int st = 0; st < 16; ++st) {
    int cur = st & 1;
    if (st < 15) stage(cur ^ 1, st + 1);

    // ---- QK^T swapped: S^T[s][t], 8 MFMA ----
    const char* Kb = (const char*)Kt[cur];
    f32x4 sf[4];
#pragma unroll
    for (int nf = 0; nf < 4; ++nf) sf[nf] = (f32x4){0.f, 0.f, 0.f, 0.f};
    __builtin_amdgcn_s_setprio(1);
#pragma unroll
    for (int nf = 0; nf < 4; ++nf) {
      int rr = nf * 16 + l15;                      // A-frag row = s
#pragma unroll
      for (int kb = 0; kb < 2; ++kb) {
        bf16x8 kf = *(const bf16x8*)(Kb + rr * 128 + ((kb * 64 + l4 * 16) ^ rsw));
        sf[nf] = mfma16(kf, qf[kb], sf[nf]);
      }
    }
    __builtin_amdgcn_s_setprio(0);

    // ---- online softmax: lane owns t=l15, s = nf*16 + l4*4 + i ----
    float mb;
    {
      float a0 = fmaxf(fmaxf(sf[0][0], sf[0][1]), fmaxf(sf[0][2], sf[0][3]));
      float a1 = fmaxf(fmaxf(sf[1][0], sf[1][1]), fmaxf(sf[1][2], sf[1][3]));
      float a2 = fmaxf(fmaxf(sf[2][0], sf[2][1]), fmaxf(sf[2][2], sf[2][3]));
      float a3 = fmaxf(fmaxf(sf[3][0], sf[3][1]), fmaxf(sf[3][2], sf[3][3]));
      mb = fmaxf(fmaxf(a0, a1), fmaxf(a2, a3));
    }
    mb = fmaxf(mb, __shfl_xor(mb, 16));
    mb = fmaxf(mb, __shfl_xor(mb, 32));
    if (!__all(mb - m_run <= 8.f)) {               // T13 defer-max
      float mn = fmaxf(m_run, mb);
      float corr = __expf(m_run - mn);
      m_run = mn;
      l_run *= corr;
#pragma unroll
      for (int cf = 0; cf < 4; ++cf)
#pragma unroll
        for (int i = 0; i < 4; ++i) oacc[cf][i] *= corr;
    }
    float sb = 0.f;
#pragma unroll
    for (int nf = 0; nf < 4; ++nf) {
      float p0 = __expf(sf[nf][0] - m_run), p1 = __expf(sf[nf][1] - m_run);
      float p2 = __expf(sf[nf][2] - m_run), p3 = __expf(sf[nf][3] - m_run);
      sb += (p0 + p1) + (p2 + p3);
      int off = nf * 32 + l4 * 8;                  // 8-aligned; rsw is 16B-granular
      *(bf16x4*)(PwRow + (off ^ rsw)) = (bf16x4){ (bf16)p0, (bf16)p1, (bf16)p2, (bf16)p3 };
    }
    sb += __shfl_xor(sb, 16);
    sb += __shfl_xor(sb, 32);
    l_run += sb;

    // ---- PV swapped: O^T += V * P, 8 MFMA ----
    const char* Vb = (const char*)Vt[cur];
    __builtin_amdgcn_s_setprio(1);
#pragma unroll
    for (int kb = 0; kb < 2; ++kb) {
      bf16x8 pf = *(const bf16x8*)(Pw + l15 * 128 + ((kb * 64 + l4 * 16) ^ rsw));
#pragma unroll
      for (int cf = 0; cf < 4; ++cf) {
        int rr = cf * 16 + l15;                    // A-frag row = c
        bf16x8 vf = *(const bf16x8*)(Vb + rr * 128 + ((kb * 64 + l4 * 16) ^ rsw));
        oacc[cf] = mfma16(vf, pf, oacc[cf]);
      }
    }
    __builtin_amdgcn_s_setprio(0);
    __syncthreads();   // drains vmcnt(0): next tile staged & this tile's readers done
  }

  float rdiv = 1.f / l_run;                        // lane-local (t = l15)
  int t = trow + l15;
#pragma unroll
  for (int cf = 0; cf < 4; ++cf) {
    bf16x4 ov = { (bf16)(oacc[cf][0] * rdiv), (bf16)(oacc[cf][1] * rdiv),
                  (bf16)(oacc[cf][2] * rdiv), (bf16)(oacc[cf][3] * rdiv) };
    *(bf16x4*)&aT[((size_t)b * 1024 + t) * 1024 + h * 64 + cf * 16 + l4 * 4] = ov;
  }
}

extern "C" void kernel_launch(void* const* d_in, const int* in_sizes, int n_in,
                              void* d_out, int out_size, void* d_ws, size_t ws_size,
                              hipStream_t stream) {
  const float* x      = (const float*)d_in[0];
  const float* gw     = (const float*)d_in[1];
  const float* gb     = (const float*)d_in[2];
  const float* qkv_w  = (const float*)d_in[3];
  const float* qkv_b  = (const float*)d_in[4];
  const float* proj_w = (const float*)d_in[5];
  const float* proj_b = (const float*)d_in[6];
  float* out = (float*)d_out;

  char* ws = (char*)d_ws;
  bf16* wq_bf = (bf16*)(ws);                          //  6 MB: 3072x1024
  bf16* wp_bf = (bf16*)(ws + 6ll  * 1024 * 1024);     //  2 MB: 1024x1024
  bf16* xnT   = (bf16*)(ws + 8ll  * 1024 * 1024);     //  8 MB: [4][1024][1024]
  bf16* qkT   = (bf16*)(ws + 16ll * 1024 * 1024);     // 16 MB: [4][1024][2048] (q|k per head)
  bf16* vC    = (bf16*)(ws + 32ll * 1024 * 1024);     //  8 MB: [64][64][1024]
  bf16* aT    = (bf16*)(ws + 40ll * 1024 * 1024);     //  8 MB: [4][1024][1024]

  hipFuncSetAttribute(reinterpret_cast<const void*>(qkv_kernel),
                      hipFuncAttributeMaxDynamicSharedMemorySize, 147456);

  cvt2_kernel<<<dim3(4096), dim3(256), 0, stream>>>(qkv_w, wq_bf, proj_w, wp_bf);
  gn_kernel<<<dim3(512), dim3(512), 0, stream>>>(x, gw, gb, xnT);
  qkv_kernel<<<dim3(256), dim3(512), 147456, stream>>>(xnT, wq_bf, qkv_b, qkT, vC);
  attn_kernel<<<dim3(512), dim3(512), 0, stream>>>(qkT, vC, aT);
  gemm_kernel<1><<<dim3(8, 8, 4), dim3(256), 0, stream>>>(aT, wp_bf, proj_b, nullptr, nullptr, x, out);
}

// Round 11
// 96.332 us; speedup vs baseline: 1.1484x; 1.1117x over previous
//
#include <hip/hip_runtime.h>
#include <hip/hip_bf16.h>

typedef __bf16 bf16;
typedef __bf16 bf16x2 __attribute__((ext_vector_type(2)));
typedef __bf16 bf16x4 __attribute__((ext_vector_type(4)));
typedef __bf16 bf16x8 __attribute__((ext_vector_type(8)));
typedef float  f32x4  __attribute__((ext_vector_type(4)));

static __device__ __forceinline__ f32x4 mfma16(bf16x8 a, bf16x8 b, f32x4 c) {
  return __builtin_amdgcn_mfma_f32_16x16x32_bf16(a, b, c, 0, 0, 0);
}

static __device__ __forceinline__ void gload_lds16(const bf16* g, bf16* l) {
  __builtin_amdgcn_global_load_lds(
      (const __attribute__((address_space(1))) void*)g,
      (__attribute__((address_space(3))) void*)l, 16, 0, 0);
}

#define VMCNT0() asm volatile("s_waitcnt vmcnt(0)" ::: "memory")
#define VMCNT2() asm volatile("s_waitcnt vmcnt(2)" ::: "memory")
#define VMCNT4() asm volatile("s_waitcnt vmcnt(4)" ::: "memory")
#define BARRIER()                                        \
  do {                                                   \
    asm volatile("" ::: "memory");                       \
    __builtin_amdgcn_s_barrier();                        \
    asm volatile("" ::: "memory");                       \
  } while (0)

// ---------------- fused: GroupNorm (blocks 0..511) + weight cast (512..2559) ----------------
__global__ __launch_bounds__(512) void pre_kernel(const float* __restrict__ x,
                                                  const float* __restrict__ gw,
                                                  const float* __restrict__ gb,
                                                  bf16* __restrict__ xnT,
                                                  const float* __restrict__ qkv_w,
                                                  bf16* __restrict__ wq,
                                                  const float* __restrict__ proj_w,
                                                  bf16* __restrict__ wp) {
  int blk = blockIdx.x;
  int tid = threadIdx.x;
  if (blk >= 512) {
    // weight cast: 2048 blocks x 512 thr x 1 float4
    int i = (blk - 512) * 512 + tid;
    const int na4 = 3072 * 1024 / 4;
    const float* src; bf16* dst;
    if (i < na4) { src = qkv_w; dst = wq; }
    else         { src = proj_w; dst = wp; i -= na4; }
    float4 v = ((const float4*)src)[i];
    bf16x4 o = { (bf16)v.x, (bf16)v.y, (bf16)v.z, (bf16)v.w };
    *(bf16x4*)(dst + 4ll * i) = o;
    return;
  }
  int id = blk;
  int b = id >> 7, g = (id >> 2) & 31, qtr = id & 3;
  const float* xb = x + ((size_t)b * 1024 + g * 32) * 1024;   // 32 ch x 1024 t
  float s = 0.f, sq = 0.f;
  const float4* x4 = (const float4*)xb;
  for (int i = tid; i < 8192; i += 512) {
    float4 v = x4[i];
    s  += v.x + v.y + v.z + v.w;
    sq += v.x * v.x + v.y * v.y + v.z * v.z + v.w * v.w;
  }
#pragma unroll
  for (int off = 32; off; off >>= 1) { s += __shfl_down(s, off); sq += __shfl_down(sq, off); }
  __shared__ float red[16];
  int wv = tid >> 6;
  if ((tid & 63) == 0) { red[wv] = s; red[8 + wv] = sq; }
  __syncthreads();
  s = 0.f; sq = 0.f;
#pragma unroll
  for (int i = 0; i < 8; ++i) { s += red[i]; sq += red[8 + i]; }
  float mean = s * (1.f / 32768.f);
  float var  = sq * (1.f / 32768.f) - mean * mean;
  float rstd = rsqrtf(var + 1e-5f);

  __shared__ bf16 tile[64][36];
  int c = tid >> 4, q = tid & 15;              // load role: ch c, t-quad q
  int r = tid >> 3, q2 = tid & 7;              // store role: row r, ch-quad q2
  float wc = gw[g * 32 + c] * rstd;
  float fb = gb[g * 32 + c] - mean * wc;
  for (int t0 = qtr * 256; t0 < qtr * 256 + 256; t0 += 64) {
    float4 v = *(const float4*)(xb + (size_t)c * 1024 + t0 + q * 4);
    tile[q * 4 + 0][c] = (bf16)(v.x * wc + fb);
    tile[q * 4 + 1][c] = (bf16)(v.y * wc + fb);
    tile[q * 4 + 2][c] = (bf16)(v.z * wc + fb);
    tile[q * 4 + 3][c] = (bf16)(v.w * wc + fb);
    __syncthreads();
    *(bf16x4*)&xnT[((size_t)b * 1024 + t0 + r) * 1024 + g * 32 + q2 * 4] =
        *(bf16x4*)&tile[r][q2 * 4];
    __syncthreads();
  }
}

// ---------------- QKV GEMM: 256x192x64, T4 counted-vmcnt pipeline (round-10) ----------------
__global__ __launch_bounds__(512, 1) void qkv_kernel(
    const bf16* __restrict__ A, const bf16* __restrict__ Bw,
    const float* __restrict__ bias,
    bf16* __restrict__ qkT, bf16* __restrict__ vC) {
  extern __shared__ __align__(16) bf16 smem[];
  // elems: A(d) @ d*16384 (256x64 each, d=0..2); B(d) @ 49152 + d*12288 (192x64)

  int tid = threadIdx.x, wid = tid >> 6, lane = tid & 63;
  int l15 = lane & 15, l4 = lane >> 4;
  int wr = wid >> 2, wc = wid & 3;
  int rsw = (l15 & 7) << 4;

  int sid = (blockIdx.x & 7) * 32 + (blockIdx.x >> 3);   // XCD chunk swizzle (256%8==0)
  int bx = sid & 15, by = (sid >> 4) & 3, z = sid >> 6;
  int m0 = by * 256, n0 = bx * 192;
  const bf16* Ab = A + (size_t)z * 1024 * 1024 + (size_t)m0 * 1024;
  const bf16* Bb = Bw + (size_t)n0 * 1024;

  int srow = tid >> 3;                    // 0..63
  int csw  = (tid & 7) ^ (srow & 7);      // pre-swizzled source chunk
  auto stageA = [&](int d, int kt) {      // 4 gloads/thread
    bf16* dst = smem + d * 16384;
    const bf16* src = Ab + kt * 64 + csw * 8;
#pragma unroll
    for (int hh = 0; hh < 2; ++hh)
#pragma unroll
      for (int L = 0; L < 2; ++L)
        gload_lds16(src + (size_t)(hh * 128 + L * 64 + srow) * 1024,
                    dst + hh * 8192 + (L * 512 + wid * 64) * 8);
  };
  auto stageB = [&](int d, int kt) {      // 3 gloads/thread
    bf16* dst = smem + 49152 + d * 12288;
    const bf16* src = Bb + kt * 64 + csw * 8;
#pragma unroll
    for (int L = 0; L < 3; ++L)
      gload_lds16(src + (size_t)(L * 64 + srow) * 1024, dst + (L * 512 + wid * 64) * 8);
  };

  f32x4 acc[8][3] = {};

  auto compute = [&](int ta, int tb) {
    const char* Ab8 = (const char*)smem + ta * 32768 + wr * 16384;
    const char* Bb8 = (const char*)smem + 98304 + tb * 24576;
    bf16x8 bfr[3][2], af[4][2];
#pragma unroll
    for (int ni = 0; ni < 3; ++ni) {
      int rb = (wc * 48 + ni * 16 + l15) * 128;
#pragma unroll
      for (int kk = 0; kk < 2; ++kk)
        bfr[ni][kk] = *(const bf16x8*)(Bb8 + rb + ((kk * 64 + l4 * 16) ^ rsw));
    }
#pragma unroll
    for (int mi = 0; mi < 4; ++mi) {
      int rb = (mi * 16 + l15) * 128;
#pragma unroll
      for (int kk = 0; kk < 2; ++kk)
        af[mi][kk] = *(const bf16x8*)(Ab8 + rb + ((kk * 64 + l4 * 16) ^ rsw));
    }
#pragma unroll
    for (int mi = 0; mi < 4; ++mi)
#pragma unroll
      for (int ni = 0; ni < 3; ++ni)
#pragma unroll
        for (int kk = 0; kk < 2; ++kk)
          acc[mi][ni] = mfma16(af[mi][kk], bfr[ni][kk], acc[mi][ni]);
#pragma unroll
    for (int mi = 0; mi < 4; ++mi) {
      int rb = ((4 + mi) * 16 + l15) * 128;
#pragma unroll
      for (int kk = 0; kk < 2; ++kk)
        af[mi][kk] = *(const bf16x8*)(Ab8 + rb + ((kk * 64 + l4 * 16) ^ rsw));
    }
#pragma unroll
    for (int mi = 0; mi < 4; ++mi)
#pragma unroll
      for (int ni = 0; ni < 3; ++ni)
#pragma unroll
        for (int kk = 0; kk < 2; ++kk)
          acc[4 + mi][ni] = mfma16(af[mi][kk], bfr[ni][kk], acc[4 + mi][ni]);
  };

  stageA(0, 0); stageB(0, 0); stageA(1, 1);
  VMCNT4();
  BARRIER();

  for (int t = 0; t < 14; ++t) {
    stageB((t + 1) & 1, t + 1);
    stageA((t + 2) % 3, t + 2);
    compute(t % 3, t & 1);
    VMCNT4();
    BARRIER();
  }
  stageB(1, 15);
  compute(2, 0);
  VMCNT0();
  BARRIER();
  compute(0, 1);

  // ---- epilogue: bias, q/k scale, split write (single head h = bx) ----
  const float scale = 0.35355339059327373f;   // 64^-0.25
  int h = bx;
#pragma unroll
  for (int ni = 0; ni < 3; ++ni) {
    int oin = wc * 48 + ni * 16;              // 0..176, wave-uniform
    float bv = bias[n0 + oin + l15];
#pragma unroll
    for (int mi = 0; mi < 8; ++mi) {
      int tb = m0 + wr * 128 + mi * 16 + l4 * 4;
      f32x4 v = acc[mi][ni];
      if (oin < 128) {                        // q|k -> qkT[b][t][h*128 + oin]
#pragma unroll
        for (int i = 0; i < 4; ++i)
          qkT[((size_t)z * 1024 + tb + i) * 2048 + h * 128 + oin + l15] =
              (bf16)((v[i] + bv) * scale);
      } else {                                // v -> vC[(b*16+h)][c][t]
        bf16x4 st = { (bf16)(v[0] + bv), (bf16)(v[1] + bv),
                      (bf16)(v[2] + bv), (bf16)(v[3] + bv) };
        *(bf16x4*)&vC[(((size_t)z * 16 + h) * 64 + (oin - 128 + l15)) * 1024 + tb] = st;
      }
    }
  }
}

// ---------------- proj GEMM: 128x128x64, T4 counted-vmcnt pipeline ----------------
// Grid = exactly 256 blocks (8m x 8n x 4z, 1/CU), 8 waves (wave tile 64x32).
// A triple-buffered (3x16KB) + B double-buffered (2x16KB) = 80 KB LDS.
// Same hazard structure as qkv; counted vmcnt(2) keeps A(t+2) in flight.
__global__ __launch_bounds__(512, 1) void proj_kernel(
    const bf16* __restrict__ A, const bf16* __restrict__ Bw,
    const float* __restrict__ bias,
    const float* __restrict__ xres, float* __restrict__ out) {
  extern __shared__ __align__(16) bf16 smem[];
  // elems: A(d) @ d*8192 (128x64, d=0..2); B(d) @ 24576 + d*8192 (128x64, d=0..1)

  int tid = threadIdx.x, wid = tid >> 6, lane = tid & 63;
  int l15 = lane & 15, l4 = lane >> 4;
  int wr = wid >> 2, wc = wid & 3;             // wave tile: rows wr*64, cols wc*32
  int rsw = (l15 & 7) << 4;

  int sid = (blockIdx.x & 7) * 32 + (blockIdx.x >> 3);   // XCD chunk swizzle
  int bx = sid & 7, by = (sid >> 3) & 7, z = sid >> 6;
  int m0 = by * 128, n0 = bx * 128;
  const bf16* Ab = A + (size_t)z * 1024 * 1024 + (size_t)m0 * 1024;
  const bf16* Bb = Bw + (size_t)n0 * 1024;

  int srow = tid >> 3;                    // 0..63
  int csw  = (tid & 7) ^ (srow & 7);      // pre-swizzled source chunk
  auto stageA = [&](int d, int kt) {      // 2 gloads/thread
    bf16* dst = smem + d * 8192;
    const bf16* src = Ab + kt * 64 + csw * 8;
#pragma unroll
    for (int L = 0; L < 2; ++L)
      gload_lds16(src + (size_t)(L * 64 + srow) * 1024, dst + (L * 512 + wid * 64) * 8);
  };
  auto stageB = [&](int d, int kt) {      // 2 gloads/thread
    bf16* dst = smem + 24576 + d * 8192;
    const bf16* src = Bb + kt * 64 + csw * 8;
#pragma unroll
    for (int L = 0; L < 2; ++L)
      gload_lds16(src + (size_t)(L * 64 + srow) * 1024, dst + (L * 512 + wid * 64) * 8);
  };

  f32x4 acc[4][2] = {};

  auto compute = [&](int ta, int tb) {
    const char* Ab8 = (const char*)smem + ta * 16384 + wr * 8192;
    const char* Bb8 = (const char*)smem + 49152 + tb * 16384;
    bf16x8 bfr[2][2], af[4][2];
#pragma unroll
    for (int ni = 0; ni < 2; ++ni) {
      int rb = (wc * 32 + ni * 16 + l15) * 128;
#pragma unroll
      for (int kk = 0; kk < 2; ++kk)
        bfr[ni][kk] = *(const bf16x8*)(Bb8 + rb + ((kk * 64 + l4 * 16) ^ rsw));
    }
#pragma unroll
    for (int mi = 0; mi < 4; ++mi) {
      int rb = (mi * 16 + l15) * 128;
#pragma unroll
      for (int kk = 0; kk < 2; ++kk)
        af[mi][kk] = *(const bf16x8*)(Ab8 + rb + ((kk * 64 + l4 * 16) ^ rsw));
    }
#pragma unroll
    for (int mi = 0; mi < 4; ++mi)
#pragma unroll
      for (int ni = 0; ni < 2; ++ni)
#pragma unroll
        for (int kk = 0; kk < 2; ++kk)
          acc[mi][ni] = mfma16(af[mi][kk], bfr[ni][kk], acc[mi][ni]);
  };

  stageA(0, 0); stageB(0, 0); stageA(1, 1);
  VMCNT2();
  BARRIER();

  for (int t = 0; t < 14; ++t) {
    stageB((t + 1) & 1, t + 1);       // issued first (must complete by tile end)
    stageA((t + 2) % 3, t + 2);       // issued LAST (allowed in flight)
    compute(t % 3, t & 1);
    VMCNT2();    // A(t+1), B(t+1) done; A(t+2)'s 2 loads may remain outstanding
    BARRIER();
  }
  stageB(1, 15);
  compute(2, 0);
  VMCNT0();
  BARRIER();
  compute(0, 1);

  // ---- epilogue: bias + residual, transposed fp32 write ----
#pragma unroll
  for (int ni = 0; ni < 2; ++ni) {
    int o = n0 + wc * 32 + ni * 16 + l15;
    float bv = bias[o];
#pragma unroll
    for (int mi = 0; mi < 4; ++mi) {
      int tb = m0 + wr * 64 + mi * 16 + l4 * 4;
      size_t base = ((size_t)z * 1024 + o) * 1024 + tb;
      float4 xr = *(const float4*)(xres + base);
      f32x4 v = acc[mi][ni];
      float4 ov = { xr.x + v[0] + bv, xr.y + v[1] + bv,
                    xr.z + v[2] + bv, xr.w + v[3] + bv };
      *(float4*)(out + base) = ov;
    }
  }
}

// ---------------- flash attention v4: 8 waves, 128 t-rows/block (round-10) ----------------
__global__ __launch_bounds__(512, 4) void attn_kernel(const bf16* __restrict__ qkT,
                                                      const bf16* __restrict__ vC,
                                                      bf16* __restrict__ aT) {
  __shared__ __align__(16) bf16 Kt[2][64 * 64];   // [buf][s][d] swizzled, 16 KB
  __shared__ __align__(16) bf16 Vt[2][64 * 64];   // [buf][c][s] swizzled, 16 KB
  __shared__ __align__(16) bf16 Pt[8][16 * 64];   // per-wave P[t][s], swizzled, 16 KB

  int id = blockIdx.x;
  int sid = (id & 7) * 64 + (id >> 3);            // bijective XCD swizzle (512 % 8 == 0)
  int head = sid >> 3, tblk = sid & 7;
  int b = head >> 4, h = head & 15;
  int t0 = tblk * 128;
  int tid = threadIdx.x, wid = tid >> 6, lane = tid & 63;
  int l15 = lane & 15, l4 = lane >> 4;
  int trow = t0 + wid * 16;

  const bf16* kbase = qkT + (size_t)b * 1024 * 2048 + h * 128 + 64;
  const bf16* vbase = vC + (size_t)(b * 16 + h) * 64 * 1024;
  char* Pw = (char*)Pt[wid];
  int rsw = (l15 & 7) << 4;                        // row-XOR for P (row = l15)
  char* PwRow = Pw + l15 * 128;

  const bf16* qrow = qkT + ((size_t)b * 1024 + trow + l15) * 2048 + h * 128;
  bf16x8 qf[2];
#pragma unroll
  for (int kb = 0; kb < 2; ++kb) qf[kb] = *(const bf16x8*)(qrow + kb * 32 + l4 * 8);

  int rl = lane >> 3;                              // row within 8-row group
  int scol = (((lane & 7) * 16) ^ (rl << 4)) >> 1; // element col, swizzle folded in
  int r8 = wid * 8 + rl;
  auto stage = [&](int buf, int st) {
    int s0 = st * 64;
    gload_lds16(kbase + (size_t)(s0 + r8) * 2048 + scol, &Kt[buf][wid * 512]);
    gload_lds16(vbase + (size_t)r8 * 1024 + s0 + scol, &Vt[buf][wid * 512]);
  };

  float m_run = -1e30f, l_run = 0.f;
  f32x4 oacc[4] = {};                              // O^T[c][t]: col t=l15, rows c

  stage(0, 0);
  __syncthreads();

  for (int st = 0; st < 16; ++st) {
    int cur = st & 1;
    if (st < 15) stage(cur ^ 1, st + 1);

    // ---- QK^T swapped: S^T[s][t], 8 MFMA ----
    const char* Kb = (const char*)Kt[cur];
    f32x4 sf[4];
#pragma unroll
    for (int nf = 0; nf < 4; ++nf) sf[nf] = (f32x4){0.f, 0.f, 0.f, 0.f};
    __builtin_amdgcn_s_setprio(1);
#pragma unroll
    for (int nf = 0; nf < 4; ++nf) {
      int rr = nf * 16 + l15;                      // A-frag row = s
#pragma unroll
      for (int kb = 0; kb < 2; ++kb) {
        bf16x8 kf = *(const bf16x8*)(Kb + rr * 128 + ((kb * 64 + l4 * 16) ^ rsw));
        sf[nf] = mfma16(kf, qf[kb], sf[nf]);
      }
    }
    __builtin_amdgcn_s_setprio(0);

    // ---- online softmax: lane owns t=l15, s = nf*16 + l4*4 + i ----
    float mb;
    {
      float a0 = fmaxf(fmaxf(sf[0][0], sf[0][1]), fmaxf(sf[0][2], sf[0][3]));
      float a1 = fmaxf(fmaxf(sf[1][0], sf[1][1]), fmaxf(sf[1][2], sf[1][3]));
      float a2 = fmaxf(fmaxf(sf[2][0], sf[2][1]), fmaxf(sf[2][2], sf[2][3]));
      float a3 = fmaxf(fmaxf(sf[3][0], sf[3][1]), fmaxf(sf[3][2], sf[3][3]));
      mb = fmaxf(fmaxf(a0, a1), fmaxf(a2, a3));
    }
    mb = fmaxf(mb, __shfl_xor(mb, 16));
    mb = fmaxf(mb, __shfl_xor(mb, 32));
    if (!__all(mb - m_run <= 8.f)) {               // T13 defer-max
      float mn = fmaxf(m_run, mb);
      float corr = __expf(m_run - mn);
      m_run = mn;
      l_run *= corr;
#pragma unroll
      for (int cf = 0; cf < 4; ++cf)
#pragma unroll
        for (int i = 0; i < 4; ++i) oacc[cf][i] *= corr;
    }
    float sb = 0.f;
#pragma unroll
    for (int nf = 0; nf < 4; ++nf) {
      float p0 = __expf(sf[nf][0] - m_run), p1 = __expf(sf[nf][1] - m_run);
      float p2 = __expf(sf[nf][2] - m_run), p3 = __expf(sf[nf][3] - m_run);
      sb += (p0 + p1) + (p2 + p3);
      int off = nf * 32 + l4 * 8;                  // 8-aligned; rsw is 16B-granular
      *(bf16x4*)(PwRow + (off ^ rsw)) = (bf16x4){ (bf16)p0, (bf16)p1, (bf16)p2, (bf16)p3 };
    }
    sb += __shfl_xor(sb, 16);
    sb += __shfl_xor(sb, 32);
    l_run += sb;

    // ---- PV swapped: O^T += V * P, 8 MFMA ----
    const char* Vb = (const char*)Vt[cur];
    __builtin_amdgcn_s_setprio(1);
#pragma unroll
    for (int kb = 0; kb < 2; ++kb) {
      bf16x8 pf = *(const bf16x8*)(Pw + l15 * 128 + ((kb * 64 + l4 * 16) ^ rsw));
#pragma unroll
      for (int cf = 0; cf < 4; ++cf) {
        int rr = cf * 16 + l15;                    // A-frag row = c
        bf16x8 vf = *(const bf16x8*)(Vb + rr * 128 + ((kb * 64 + l4 * 16) ^ rsw));
        oacc[cf] = mfma16(vf, pf, oacc[cf]);
      }
    }
    __builtin_amdgcn_s_setprio(0);
    __syncthreads();
  }

  float rdiv = 1.f / l_run;                        // lane-local (t = l15)
  int t = trow + l15;
#pragma unroll
  for (int cf = 0; cf < 4; ++cf) {
    bf16x4 ov = { (bf16)(oacc[cf][0] * rdiv), (bf16)(oacc[cf][1] * rdiv),
                  (bf16)(oacc[cf][2] * rdiv), (bf16)(oacc[cf][3] * rdiv) };
    *(bf16x4*)&aT[((size_t)b * 1024 + t) * 1024 + h * 64 + cf * 16 + l4 * 4] = ov;
  }
}

extern "C" void kernel_launch(void* const* d_in, const int* in_sizes, int n_in,
                              void* d_out, int out_size, void* d_ws, size_t ws_size,
                              hipStream_t stream) {
  const float* x      = (const float*)d_in[0];
  const float* gw     = (const float*)d_in[1];
  const float* gb     = (const float*)d_in[2];
  const float* qkv_w  = (const float*)d_in[3];
  const float* qkv_b  = (const float*)d_in[4];
  const float* proj_w = (const float*)d_in[5];
  const float* proj_b = (const float*)d_in[6];
  float* out = (float*)d_out;

  char* ws = (char*)d_ws;
  bf16* wq_bf = (bf16*)(ws);                          //  6 MB: 3072x1024
  bf16* wp_bf = (bf16*)(ws + 6ll  * 1024 * 1024);     //  2 MB: 1024x1024
  bf16* xnT   = (bf16*)(ws + 8ll  * 1024 * 1024);     //  8 MB: [4][1024][1024]
  bf16* qkT   = (bf16*)(ws + 16ll * 1024 * 1024);     // 16 MB: [4][1024][2048] (q|k per head)
  bf16* vC    = (bf16*)(ws + 32ll * 1024 * 1024);     //  8 MB: [64][64][1024]
  bf16* aT    = (bf16*)(ws + 40ll * 1024 * 1024);     //  8 MB: [4][1024][1024]

  hipFuncSetAttribute(reinterpret_cast<const void*>(qkv_kernel),
                      hipFuncAttributeMaxDynamicSharedMemorySize, 147456);
  hipFuncSetAttribute(reinterpret_cast<const void*>(proj_kernel),
                      hipFuncAttributeMaxDynamicSharedMemorySize, 81920);

  pre_kernel<<<dim3(2560), dim3(512), 0, stream>>>(x, gw, gb, xnT, qkv_w, wq_bf, proj_w, wp_bf);
  qkv_kernel<<<dim3(256), dim3(512), 147456, stream>>>(xnT, wq_bf, qkv_b, qkT, vC);
  attn_kernel<<<dim3(512), dim3(512), 0, stream>>>(qkT, vC, aT);
  proj_kernel<<<dim3(256), dim3(512), 81920, stream>>>(aT, wp_bf, proj_b, x, out);
}